// Round 1
// baseline (139.777 us; speedup 1.0000x reference)
//
#include <hip/hip_runtime.h>
#include <math.h>

// Problem constants (from reference)
#define A_ 3
#define H_ 128
#define W_ 128
#define C_ 2
#define ATTRS 7
#define B_ 64
#define CELLS_PER_BATCH (A_*H_*W_)          // 49152
#define TOTAL_CELLS (B_*CELLS_PER_BATCH)    // 3145728

#define NBLK 1536
#define NTHR 256
#define ITERS (TOTAL_CELLS / (NBLK*NTHR))   // 8
#define NSLOTS 32

__global__ __launch_bounds__(192) void zero_ws_k(float* ws) {
    ws[threadIdx.x] = 0.0f;   // 32 slots * 6 metrics = 192 floats
}

__global__ __launch_bounds__(NTHR) void yolo_main_k(
    const float* __restrict__ outp,
    const float* __restrict__ boxes,
    const int*   __restrict__ labels,
    const float* __restrict__ areas,
    float* __restrict__ ws)
{
    __shared__ float4 s_tile[448];      // 256 cells * 7 floats = 1792 floats = 448 float4
    __shared__ float  s_red[4][6];
    const int tid = threadIdx.x;

    float accX = 0.f, accY = 0.f, accW = 0.f, accH = 0.f, accC = 0.f, accK = 0.f;

    for (int it = 0; it < ITERS; ++it) {
        const int base = (blockIdx.x + it * NBLK) * NTHR;   // first cell of this tile
        if (it) __syncthreads();        // protect LDS tile reuse
        // ---- stage 7168 B tile: fully coalesced float4 loads ----
        const float4* gp = (const float4*)(outp + (size_t)base * ATTRS);
        s_tile[tid] = gp[tid];
        if (tid < 192) s_tile[tid + 256] = gp[tid + 256];
        __syncthreads();

        // ---- per-block-uniform target setup (b is uniform: 49152 % 256 == 0) ----
        const int b     = base / CELLS_PER_BATCH;
        const int rbase = base - b * CELLS_PER_BATCH;

        float cxA[2], cyA[2], bwA[2], bhA[2], atA[2], t5A[2];
        int   baA[2], cXA[2], cYA[2];
        #pragma unroll
        for (int t = 0; t < 2; ++t) {
            const float x1 = boxes[b*8 + t*4 + 0];
            const float y1 = boxes[b*8 + t*4 + 1];
            const float x2 = boxes[b*8 + t*4 + 2];
            const float y2 = boxes[b*8 + t*4 + 3];
            const float cx = (x1 + x2) * 0.5f, cy = (y1 + y2) * 0.5f;
            const float bw = x2 - x1,          bh = y2 - y1;
            cxA[t] = cx; cyA[t] = cy; bwA[t] = bw; bhA[t] = bh;
            atA[t] = (bw - cx) * (bh - cy);    // reference's "area_t" quirk
            const float ar = areas[b*2 + t];
            // argmin(|anchor_area - ar|), first-min tie-break (strict <)
            const float d0 = fabsf(10440.f - ar);
            const float d1 = fabsf(30888.f - ar);
            const float d2 = fabsf(121598.f - ar);
            int ba = 0; float bd = d0;
            if (d1 < bd) { ba = 1; bd = d1; }
            if (d2 < bd) { ba = 2; }
            baA[t] = ba;
            cXA[t] = (int)((bw - cx) * 0.125f);   // /STRIDE_W==8, trunc toward 0
            cYA[t] = (int)((bh - cy) * 0.125f);
            const int lab = labels[b*2 + t];
            // matched[...,5] = one_hot[...,1]: t0 -> (lab==1), t1 -> (lab-1==1)
            t5A[t] = (t == 0) ? (lab == 1 ? 1.f : 0.f) : (lab == 2 ? 1.f : 0.f);
        }

        // ---- per-cell work ----
        const int r = rbase + tid;
        const int a = r >> 14;            // / (H*W)
        const int i = (r >> 7) & 127;     // H index (gx)
        const int j = r & 127;            // W index (gy)
        const float* sp = ((const float*)s_tile) + tid * ATTRS; // stride-7 dwords: 2-way bank alias (free)
        const float xr = sp[0], yr = sp[1], w = sp[2], h = sp[3];
        const float conf = sp[4], c0 = sp[5], c1 = sp[6];

        const float fi = (float)i, fj = (float)j;
        const float x = xr - fi, y = yr - fj;
        const float hw = 0.5f * w, hh = 0.5f * h;
        const float px1 = x - hw, px2 = x + hw;
        const float py1 = y - hh, py2 = y + hh;
        const float areaP = (px2 - px1) * (py2 - py1);

        bool e[2]; float iou[2];
        #pragma unroll
        for (int t = 0; t < 2; ++t) {
            e[t] = (a == baA[t]) && (i == cXA[t]) && (j == cYA[t]);
            // reference quirk: (tx1,ty1,tx2,ty2) = (cx,cy,bw,bh)
            const float ix = fmaxf(fminf(px2, bwA[t]) - fmaxf(px1, cxA[t]), 0.f);
            const float iy = fmaxf(fminf(py2, bhA[t]) - fmaxf(py1, cyA[t]), 0.f);
            const float in_ = ix * iy;
            iou[t] = in_ / (areaP + atA[t] - in_ + 1e-16f);
        }
        const bool  exact = e[0] || e[1];
        const float miou  = fmaxf(iou[0], iou[1]);
        const bool  suppress = (!exact) && (miou > 0.5f);

        if (exact) {                       // rare: <= 2 cells per batch
            const int t = e[1] ? 1 : 0;    // .at[].set loop: t=1 overwrites t=0
            const float dx = x - (cxA[t] - fi); accX += dx * dx;
            const float dy = y - (cyA[t] - fj); accY += dy * dy;
            const float dw = w - bwA[t];        accW += dw * dw;
            const float dh = h - bhA[t];        accH += dh * dh;
            accC += fmaxf(logf(conf), -100.f);          // tConf=1
            if (t5A[t] != 0.f)                          // same t for both channels
                accK += fmaxf(logf(c0), -100.f) + fmaxf(logf(c1), -100.f);
            else
                accK += fmaxf(log1pf(-c0), -100.f) + fmaxf(log1pf(-c1), -100.f);
        } else if (!suppress) {
            accC += fmaxf(log1pf(-conf), -100.f);       // tConf=0, p=conf
        }
        // suppressed: p=0,t=0 -> term 0; non-exact cls: p=0,t=0 -> term 0
    }

    // ---- block reduction: wave shuffle -> LDS -> scatter atomics ----
    float v[6] = {accX, accY, accW, accH, accC, accK};
    #pragma unroll
    for (int m = 0; m < 6; ++m) {
        float s = v[m];
        #pragma unroll
        for (int off = 32; off > 0; off >>= 1) s += __shfl_down(s, off, 64);
        v[m] = s;
    }
    const int wid = tid >> 6;
    if ((tid & 63) == 0) {
        #pragma unroll
        for (int m = 0; m < 6; ++m) s_red[wid][m] = v[m];
    }
    __syncthreads();
    if (tid < 6) {
        const float s = s_red[0][tid] + s_red[1][tid] + s_red[2][tid] + s_red[3][tid];
        atomicAdd(&ws[(blockIdx.x & (NSLOTS - 1)) * 6 + tid], s);
    }
}

__global__ __launch_bounds__(64) void finalize_k(const float* __restrict__ ws,
                                                 float* __restrict__ o)
{
    if (threadIdx.x == 0) {
        float s0=0,s1=0,s2=0,s3=0,s4=0,s5=0;
        for (int k = 0; k < NSLOTS; ++k) {
            s0 += ws[k*6+0]; s1 += ws[k*6+1]; s2 += ws[k*6+2];
            s3 += ws[k*6+3]; s4 += ws[k*6+4]; s5 += ws[k*6+5];
        }
        const float N = (float)TOTAL_CELLS;
        const float xL = s0 / N, yL = s1 / N, wL = s2 / N, hL = s3 / N;
        const float confL = -s4 / N;
        const float clsL  = -s5 / (N * (float)C_);
        o[0] = 2.5f * (xL + yL) + 2.5f * (wL + hL) + confL + clsL;
        o[1] = xL; o[2] = yL; o[3] = wL; o[4] = hL; o[5] = confL; o[6] = clsL;
    }
}

extern "C" void kernel_launch(void* const* d_in, const int* in_sizes, int n_in,
                              void* d_out, int out_size, void* d_ws, size_t ws_size,
                              hipStream_t stream) {
    const float* outp   = (const float*)d_in[0];
    const float* boxes  = (const float*)d_in[1];
    const int*   labels = (const int*)d_in[2];
    const float* areas  = (const float*)d_in[3];
    float* ws = (float*)d_ws;     // 32 slots * 6 sums = 768 B
    float* o  = (float*)d_out;    // 7 float32 outputs

    zero_ws_k<<<1, 192, 0, stream>>>(ws);
    yolo_main_k<<<NBLK, NTHR, 0, stream>>>(outp, boxes, labels, areas, ws);
    finalize_k<<<1, 64, 0, stream>>>(ws, o);
}